// Round 6
// baseline (1042.422 us; speedup 1.0000x reference)
//
#include <hip/hip_runtime.h>
#include <hip/hip_cooperative_groups.h>
#include <cstdint>

namespace cg = cooperative_groups;

#define N_NODES 10000
#define N_EDGES 320000
#define DIN 512
#define DOUT 256
#define NB 512           // 2 blocks/CU needed -- large co-residency margin
#define NTH 256
#define N_TILES 632      // 79 m-tiles (128 rows) x 8 n-tiles (32 cols)

using short8 = __attribute__((ext_vector_type(8))) short;
using f32x4  = __attribute__((ext_vector_type(4))) float;
typedef unsigned short ushort_t;

static __device__ __forceinline__ unsigned short f2bf(float f) {
  unsigned u = __builtin_bit_cast(unsigned, f);
  u += 0x7fffu + ((u >> 16) & 1u);   // round-to-nearest-even
  return (unsigned short)(u >> 16);
}
static __device__ __forceinline__ float bf2f(unsigned short s) {
  unsigned u = ((unsigned)s) << 16;
  return __builtin_bit_cast(float, u);
}

// int64-vs-int32 edge_index layout detect (odd u32 words all zero => int64).
static __device__ __forceinline__ int detect64(const unsigned* ei) {
  unsigned z = 0;
  #pragma unroll
  for (int i = 1; i < 32; i += 2) z |= ei[i];
  return z == 0u;
}
static __device__ __forceinline__ int load_idx(const unsigned* ei, int i, int is64) {
  return is64 ? (int)ei[2 * i] : (int)ei[i];
}

// ---------------------------------------------------------------------------
// GEMM tile: C[128 x 32]. B panel 32 rows x 512 k in LDS (pad +8), loaded per
// tile. Wave = 32 rows x 32 cols; per BK=32: 2 global A-loads (16B/lane),
// 2 ds_read_b128, 4 MFMA. SPLIT: A = [A0 | A1] at k=256 (both ld 256).
template<int RELU, int ADDB, int OUTF, int OUTB, int SPLIT>
static __device__ void gemm_tile(int t, const ushort_t* __restrict__ A0,
                                 const ushort_t* __restrict__ A1,
                                 const ushort_t* __restrict__ BT,
                                 const float* __restrict__ bias,
                                 const ushort_t* __restrict__ addB,
                                 float* __restrict__ outF,
                                 ushort_t* __restrict__ outB,
                                 ushort_t* Bs, int M) {
  const int tid  = threadIdx.x;
  const int lane = tid & 63;
  const int w    = tid >> 6;
  const int bn   = (t & 7) * 32;
  const int mbase = (t >> 3) * 128 + w * 32;

  __syncthreads();   // protect previous tile's LDS reads from restaging
  // stage B panel: 32 rows x 512 = 2048 uint4, 8 per thread
  #pragma unroll
  for (int i = 0; i < 8; ++i) {
    int c   = i * 256 + tid;
    int row = c >> 6;
    int c8  = (c & 63) * 8;
    *(uint4*)&Bs[row * 520 + c8] = *(const uint4*)(BT + (size_t)(bn + row) * 512 + c8);
  }
  __syncthreads();

  f32x4 acc[2][2] = {};
  const int mrow = lane & 15;
  const int k8   = (lane >> 4) * 8;

  #pragma unroll 4
  for (int kt = 0; kt < 512; kt += 32) {
    const ushort_t* Asrc;
    int acol, ald;
    if (SPLIT) {
      if (kt < 256) { Asrc = A0; acol = kt; } else { Asrc = A1; acol = kt - 256; }
      ald = 256;
    } else {
      Asrc = A0; acol = kt; ald = 512;
    }
    short8 a[2], bb[2];
    #pragma unroll
    for (int s = 0; s < 2; ++s) {
      int row = mbase + s * 16 + mrow;
      short8 av = {};
      if (row < M) av = *(const short8*)(Asrc + (size_t)row * ald + acol + k8);
      a[s] = av;
    }
    #pragma unroll
    for (int ni = 0; ni < 2; ++ni)
      bb[ni] = *(const short8*)&Bs[(ni * 16 + mrow) * 520 + kt + k8];
    #pragma unroll
    for (int s = 0; s < 2; ++s)
      #pragma unroll
      for (int ni = 0; ni < 2; ++ni)
        acc[s][ni] = __builtin_amdgcn_mfma_f32_16x16x32_bf16(a[s], bb[ni], acc[s][ni], 0, 0, 0);
  }

  // C/D layout: col = lane&15, row = (lane>>4)*4 + reg   [m89-verified]
  const int cq   = lane >> 4;
  const int ccol = lane & 15;
  #pragma unroll
  for (int ni = 0; ni < 2; ++ni) {
    int gcol = bn + ni * 16 + ccol;
    float bv = bias[gcol];
    #pragma unroll
    for (int s = 0; s < 2; ++s) {
      #pragma unroll
      for (int r = 0; r < 4; ++r) {
        int grow = mbase + s * 16 + cq * 4 + r;
        if (grow < M) {
          float v = acc[s][ni][r] + bv;
          if (RELU) v = fmaxf(v, 0.f);
          if (ADDB) v += bf2f(addB[(size_t)grow * DOUT + gcol]);
          if (OUTF) outF[(size_t)grow * DOUT + gcol] = v;
          if (OUTB) outB[(size_t)grow * DOUT + gcol] = f2bf(v);
        }
      }
    }
  }
}

// CSR mean-aggregate: one wave per node, lane = 4 cols, 4-edge unroll,
// grid-stride (NB*4 = 2048 waves).
static __device__ void agg_phase(const ushort_t* __restrict__ h,
                                 const int* __restrict__ rowp,
                                 const int* __restrict__ srcs,
                                 ushort_t* __restrict__ mean) {
  const int lane = threadIdx.x & 63;
  const int gw   = blockIdx.x * 4 + (threadIdx.x >> 6);
  for (int node = gw; node < N_NODES; node += NB * 4) {
    int beg = rowp[node], end = rowp[node + 1];
    float a0 = 0.f, a1 = 0.f, a2 = 0.f, a3 = 0.f;
    int j = beg;
    for (; j + 4 <= end; j += 4) {
      int s0 = srcs[j], s1 = srcs[j + 1], s2 = srcs[j + 2], s3 = srcs[j + 3];
      uint2 u0 = *(const uint2*)(h + (size_t)s0 * 256 + lane * 4);
      uint2 u1 = *(const uint2*)(h + (size_t)s1 * 256 + lane * 4);
      uint2 u2 = *(const uint2*)(h + (size_t)s2 * 256 + lane * 4);
      uint2 u3 = *(const uint2*)(h + (size_t)s3 * 256 + lane * 4);
      a0 += bf2f(u0.x & 0xffff) + bf2f(u1.x & 0xffff) + bf2f(u2.x & 0xffff) + bf2f(u3.x & 0xffff);
      a1 += bf2f(u0.x >> 16)    + bf2f(u1.x >> 16)    + bf2f(u2.x >> 16)    + bf2f(u3.x >> 16);
      a2 += bf2f(u0.y & 0xffff) + bf2f(u1.y & 0xffff) + bf2f(u2.y & 0xffff) + bf2f(u3.y & 0xffff);
      a3 += bf2f(u0.y >> 16)    + bf2f(u1.y >> 16)    + bf2f(u2.y >> 16)    + bf2f(u3.y >> 16);
    }
    for (; j < end; ++j) {
      int s0 = srcs[j];
      uint2 u0 = *(const uint2*)(h + (size_t)s0 * 256 + lane * 4);
      a0 += bf2f(u0.x & 0xffff);
      a1 += bf2f(u0.x >> 16);
      a2 += bf2f(u0.y & 0xffff);
      a3 += bf2f(u0.y >> 16);
    }
    int d = end - beg;
    float inv = 1.0f / (float)(d > 1 ? d : 1);
    uint2 o;
    o.x = (unsigned)f2bf(a0 * inv) | ((unsigned)f2bf(a1 * inv) << 16);
    o.y = (unsigned)f2bf(a2 * inv) | ((unsigned)f2bf(a3 * inv) << 16);
    *(uint2*)(mean + (size_t)node * 256 + lane * 4) = o;
  }
}

// ---------------------------------------------------------------------------
// P0 work counts: deg-zero (10240) | weight transpose 3*256*512 (393216) |
// x cast: 10000*512 floats / 4 per chunk = 1,280,000 chunks.
// R4/R5 BUG was here: x-cast count was 320000 -> 75% of xb left as 0xAA
// poison -> deterministic absmax 3.93 in BOTH rounds. Fixed.
#define P0_XCHUNKS 1280000
#define P0_TOT (10240 + 393216 + P0_XCHUNKS)

__global__ __launch_bounds__(256, 4) void mega(
    const float* __restrict__ x, const unsigned* __restrict__ ei,
    const float* __restrict__ W0, const float* __restrict__ b0,
    const float* __restrict__ Wl1, const float* __restrict__ bl1,
    const float* __restrict__ Wr1,
    const float* __restrict__ Wl2, const float* __restrict__ bl2,
    const float* __restrict__ Wr2,
    ushort_t* __restrict__ xb, ushort_t* __restrict__ hb,
    ushort_t* __restrict__ o1b, ushort_t* __restrict__ mb,
    ushort_t* __restrict__ W0T, ushort_t* __restrict__ WT1,
    ushort_t* __restrict__ WT2,
    int* __restrict__ deg, int* __restrict__ rowp, int* __restrict__ cursor,
    int* __restrict__ srcs,
    float* __restrict__ out1, float* __restrict__ out2) {
  __shared__ ushort_t smem[32 * 520];   // 33,280 B; aliased per phase

  cg::grid_group grid = cg::this_grid();
  const int b   = blockIdx.x;
  const int tid = threadIdx.x;

  // ---- P0: zero deg | weight transpose->bf16 | x cast->bf16 --------------
  for (int idx = b * NTH + tid; idx < P0_TOT; idx += NB * NTH) {
    if (idx < 10240) {
      if (idx < N_NODES) deg[idx] = 0;
    } else if (idx < 10240 + 393216) {
      int g = idx - 10240;
      int mat = g >> 17;
      int r = g & 131071;
      int n = r >> 9, k = r & 511;
      float v;
      ushort_t* dst;
      if (mat == 0)      { v = W0[k * 256 + n]; dst = W0T; }
      else if (mat == 1) { v = (k < 256) ? Wl1[k * 256 + n] : Wr1[(k - 256) * 256 + n]; dst = WT1; }
      else               { v = (k < 256) ? Wl2[k * 256 + n] : Wr2[(k - 256) * 256 + n]; dst = WT2; }
      dst[r] = f2bf(v);
    } else {
      int u = idx - (10240 + 393216);   // 0 .. 1,279,999 (4 floats each)
      float4 f = *(const float4*)(x + (size_t)u * 4);
      uint2 o;
      o.x = (unsigned)f2bf(f.x) | ((unsigned)f2bf(f.y) << 16);
      o.y = (unsigned)f2bf(f.z) | ((unsigned)f2bf(f.w) << 16);
      *(uint2*)(xb + (size_t)u * 4) = o;
    }
  }
  __threadfence();
  grid.sync();

  // ---- P1: GEMM1 (h = xb@W0T + b0 -> hb) then degree histogram -----------
  for (int t = b; t < N_TILES; t += NB)
    gemm_tile<0, 0, 0, 1, 0>(t, xb, nullptr, W0T, b0, nullptr, nullptr, hb,
                             smem, N_NODES);
  {
    int is64 = detect64(ei);
    for (int e = b * NTH + tid; e < N_EDGES; e += NB * NTH) {
      int d = load_idx(ei, N_EDGES + e, is64);
      atomicAdd(&deg[d], 1);
    }
  }
  __threadfence();
  grid.sync();

  // ---- P2: exclusive scan deg -> rowp/cursor (block 0 only) --------------
  if (b == 0) {
    int* ibuf = (int*)smem;
    int base = tid * 40;
    int s = 0;
    for (int i = 0; i < 40; ++i) {
      int g = base + i;
      if (g < N_NODES) s += deg[g];
    }
    ibuf[tid] = s;
    __syncthreads();
    #pragma unroll
    for (int o = 1; o < 256; o <<= 1) {
      int v = (tid >= o) ? ibuf[tid - o] : 0;
      __syncthreads();
      ibuf[tid] += v;
      __syncthreads();
    }
    int run = ibuf[tid] - s;
    for (int i = 0; i < 40; ++i) {
      int g = base + i;
      if (g < N_NODES) {
        rowp[g] = run;
        cursor[g] = run;
        run += deg[g];
      }
    }
    if (tid == 0) rowp[N_NODES] = N_EDGES;
  }
  __threadfence();
  grid.sync();

  // ---- P3: scatter edges into CSR buckets --------------------------------
  {
    int is64 = detect64(ei);
    for (int e = b * NTH + tid; e < N_EDGES; e += NB * NTH) {
      int d = load_idx(ei, N_EDGES + e, is64);
      int s = load_idx(ei, e, is64);
      int pos = atomicAdd(&cursor[d], 1);
      srcs[pos] = s;
    }
  }
  __threadfence();
  grid.sync();

  // ---- P4: mean1 = scatter-mean(h) -> mb ---------------------------------
  agg_phase(hb, rowp, srcs, mb);
  __threadfence();
  grid.sync();

  // ---- P5: out1 = relu([mb|hb]@WT1 + bl1) + hb ---------------------------
  for (int t = b; t < N_TILES; t += NB)
    gemm_tile<1, 1, 1, 1, 1>(t, mb, hb, WT1, bl1, hb, out1, o1b, smem, N_NODES);
  __threadfence();
  grid.sync();

  // ---- P6: mean2 = scatter-mean(out1) -> mb ------------------------------
  agg_phase(o1b, rowp, srcs, mb);
  __threadfence();
  grid.sync();

  // ---- P7: out2 = [mb|o1b]@WT2 + bl2 + o1b -------------------------------
  for (int t = b; t < N_TILES; t += NB)
    gemm_tile<0, 1, 1, 0, 1>(t, mb, o1b, WT2, bl2, o1b, out2, nullptr, smem,
                             N_NODES);
}

// ---------------------------------------------------------------------------
extern "C" void kernel_launch(void* const* d_in, const int* in_sizes, int n_in,
                              void* d_out, int out_size, void* d_ws, size_t ws_size,
                              hipStream_t stream) {
  const float*    x   = (const float*)d_in[0];
  const unsigned* ei  = (const unsigned*)d_in[1];
  const float*    W0  = (const float*)d_in[2];
  const float*    b0  = (const float*)d_in[3];
  const float*    Wl1 = (const float*)d_in[4];
  const float*    bl1 = (const float*)d_in[5];
  const float*    Wr1 = (const float*)d_in[6];
  const float*    Wl2 = (const float*)d_in[7];
  const float*    bl2 = (const float*)d_in[8];
  const float*    Wr2 = (const float*)d_in[9];

  char* ws = (char*)d_ws;
  size_t off = 0;
  auto alloc = [&](size_t bytes) {
    char* p = ws + off;
    off += (bytes + 255) & ~(size_t)255;
    return p;
  };
  ushort_t* xb  = (ushort_t*)alloc((size_t)N_NODES * 512 * 2);
  ushort_t* hb  = (ushort_t*)alloc((size_t)N_NODES * 256 * 2);
  ushort_t* o1b = (ushort_t*)alloc((size_t)N_NODES * 256 * 2);
  ushort_t* mb  = (ushort_t*)alloc((size_t)N_NODES * 256 * 2);
  ushort_t* W0T = (ushort_t*)alloc(256 * 512 * 2);
  ushort_t* WT1 = (ushort_t*)alloc(256 * 512 * 2);
  ushort_t* WT2 = (ushort_t*)alloc(256 * 512 * 2);
  int* deg    = (int*)alloc(N_NODES * 4);
  int* rowp   = (int*)alloc((N_NODES + 1) * 4);
  int* cursor = (int*)alloc(N_NODES * 4);
  int* srcs   = (int*)alloc((size_t)N_EDGES * 4);

  float* out1 = (float*)d_out;
  float* out2 = out1 + (size_t)N_NODES * DOUT;

  void* args[] = {
    (void*)&x, (void*)&ei, (void*)&W0, (void*)&b0,
    (void*)&Wl1, (void*)&bl1, (void*)&Wr1,
    (void*)&Wl2, (void*)&bl2, (void*)&Wr2,
    (void*)&xb, (void*)&hb, (void*)&o1b, (void*)&mb,
    (void*)&W0T, (void*)&WT1, (void*)&WT2,
    (void*)&deg, (void*)&rowp, (void*)&cursor, (void*)&srcs,
    (void*)&out1, (void*)&out2,
  };
  hipLaunchCooperativeKernel((void*)mega, dim3(NB), dim3(NTH), args, 0, stream);
}

// Round 7
// 435.424 us; speedup vs baseline: 2.3940x; 2.3940x over previous
//
#include <hip/hip_runtime.h>
#include <cstdint>

#define N_NODES 10000
#define N_EDGES 320000
#define DIN 512
#define DOUT 256
#define NB 512           // 2 blocks/CU x 256 CUs -- all co-resident (LDS allows exactly 2)
#define NTH 256
#define CAP 96           // CSR bucket capacity; deg ~ Poisson(32), P(>96) ~ 1e-26
#define N_TILES 316      // 79 m-tiles (128 rows) x 4 n-tiles (64 cols)

using short8 = __attribute__((ext_vector_type(8))) short;
using f32x4  = __attribute__((ext_vector_type(4))) float;
typedef unsigned short ushort_t;

static __device__ __forceinline__ unsigned short f2bf(float f) {
  unsigned u = __builtin_bit_cast(unsigned, f);
  u += 0x7fffu + ((u >> 16) & 1u);   // round-to-nearest-even
  return (unsigned short)(u >> 16);
}
static __device__ __forceinline__ float bf2f(unsigned short s) {
  unsigned u = ((unsigned)s) << 16;
  return __builtin_bit_cast(float, u);
}

// int64-vs-int32 edge_index layout detect (odd u32 words all zero => int64).
static __device__ __forceinline__ int detect64(const unsigned* ei) {
  unsigned z = 0;
  #pragma unroll
  for (int i = 1; i < 32; i += 2) z |= ei[i];
  return z == 0u;
}
static __device__ __forceinline__ int load_idx(const unsigned* ei, int i, int is64) {
  return is64 ? (int)ei[2 * i] : (int)ei[i];
}

// Grid barrier, fence ONCE PER BLOCK (R6 post-mortem: per-thread threadfence
// = wbl2/inv tag-walk storm = 974us). __syncthreads drains each wave's
// vmcnt first, so thread0's release-writeback covers the block's stores;
// thread0's acquire-invalidate covers the block's CU-shared L1 + XCD L2.
// Sequencing correctness evidenced by R4==R5 bit-identical results.
static __device__ __forceinline__ void gridbar(int* bar, int slot) {
  __syncthreads();
  if (threadIdx.x == 0) {
    __hip_atomic_fetch_add(&bar[slot], 1, __ATOMIC_RELEASE, __HIP_MEMORY_SCOPE_AGENT);
    while (__hip_atomic_load(&bar[slot], __ATOMIC_RELAXED, __HIP_MEMORY_SCOPE_AGENT) < NB)
      __builtin_amdgcn_s_sleep(8);
    (void)__hip_atomic_load(&bar[slot], __ATOMIC_ACQUIRE, __HIP_MEMORY_SCOPE_AGENT);
  }
  __syncthreads();
}

// ---------------------------------------------------------------------------
// GEMM tile: C[128 x 64]. B panel 64 rows x 512 k in LDS (pad +8; 66,560 B,
// compiles+runs on gfx950 -- R3 empirical). 316 tiles => 1 tile/block max.
// Wave = 32 rows x 64 cols; per BK=32: 2 global A-loads (16B/lane),
// 4 ds_read_b128, 8 MFMA. SPLIT: A = [A0 | A1] at k=256 (both ld 256).
template<int RELU, int ADDB, int OUTF, int OUTB, int SPLIT>
static __device__ void gemm_tile(int t, const ushort_t* __restrict__ A0,
                                 const ushort_t* __restrict__ A1,
                                 const ushort_t* __restrict__ BT,
                                 const float* __restrict__ bias,
                                 const ushort_t* __restrict__ addB,
                                 float* __restrict__ outF,
                                 ushort_t* __restrict__ outB,
                                 ushort_t* Bs, int M) {
  const int tid  = threadIdx.x;
  const int lane = tid & 63;
  const int w    = tid >> 6;
  const int bn   = (t & 3) * 64;
  const int mbase = (t >> 2) * 128 + w * 32;

  // stage B panel: 64 rows x 512 k = 4096 uint4 chunks, 16 per thread
  #pragma unroll
  for (int i = 0; i < 16; ++i) {
    int c   = i * 256 + tid;
    int row = c >> 6;
    int c8  = (c & 63) * 8;
    *(uint4*)&Bs[row * 520 + c8] = *(const uint4*)(BT + (size_t)(bn + row) * 512 + c8);
  }
  __syncthreads();

  f32x4 acc[2][4] = {};
  const int mrow = lane & 15;
  const int k8   = (lane >> 4) * 8;

  #pragma unroll 4
  for (int kt = 0; kt < 512; kt += 32) {
    const ushort_t* Asrc;
    int acol, ald;
    if (SPLIT) {
      if (kt < 256) { Asrc = A0; acol = kt; } else { Asrc = A1; acol = kt - 256; }
      ald = 256;
    } else {
      Asrc = A0; acol = kt; ald = 512;
    }
    short8 a[2], bb[4];
    #pragma unroll
    for (int s = 0; s < 2; ++s) {
      int row = mbase + s * 16 + mrow;
      short8 av = {};
      if (row < M) av = *(const short8*)(Asrc + (size_t)row * ald + acol + k8);
      a[s] = av;
    }
    #pragma unroll
    for (int ni = 0; ni < 4; ++ni)
      bb[ni] = *(const short8*)&Bs[(ni * 16 + mrow) * 520 + kt + k8];
    #pragma unroll
    for (int s = 0; s < 2; ++s)
      #pragma unroll
      for (int ni = 0; ni < 4; ++ni)
        acc[s][ni] = __builtin_amdgcn_mfma_f32_16x16x32_bf16(a[s], bb[ni], acc[s][ni], 0, 0, 0);
  }

  // C/D layout: col = lane&15, row = (lane>>4)*4 + reg   [m89-verified]
  const int cq   = lane >> 4;
  const int ccol = lane & 15;
  #pragma unroll
  for (int ni = 0; ni < 4; ++ni) {
    int gcol = bn + ni * 16 + ccol;
    float bv = bias[gcol];
    #pragma unroll
    for (int s = 0; s < 2; ++s) {
      #pragma unroll
      for (int r = 0; r < 4; ++r) {
        int grow = mbase + s * 16 + cq * 4 + r;
        if (grow < M) {
          float v = acc[s][ni][r] + bv;
          if (RELU) v = fmaxf(v, 0.f);
          if (ADDB) v += bf2f(addB[(size_t)grow * DOUT + gcol]);
          if (OUTF) outF[(size_t)grow * DOUT + gcol] = v;
          if (OUTB) outB[(size_t)grow * DOUT + gcol] = f2bf(v);
        }
      }
    }
  }
  __syncthreads();   // LDS reuse safety for any later phase
}

// Bucket-CSR mean-aggregate: one wave per node, lane = 4 cols, 4-edge unroll.
static __device__ void agg_phase(const ushort_t* __restrict__ h,
                                 const int* __restrict__ cnt,
                                 const int* __restrict__ srcs,
                                 ushort_t* __restrict__ mean) {
  const int lane = threadIdx.x & 63;
  const int gw   = blockIdx.x * 4 + (threadIdx.x >> 6);
  for (int node = gw; node < N_NODES; node += NB * 4) {
    int d = cnt[node];
    int nread = d < CAP ? d : CAP;
    const int* sp = srcs + (size_t)node * CAP;
    float a0 = 0.f, a1 = 0.f, a2 = 0.f, a3 = 0.f;
    int j = 0;
    for (; j + 4 <= nread; j += 4) {
      int s0 = sp[j], s1 = sp[j + 1], s2 = sp[j + 2], s3 = sp[j + 3];
      uint2 u0 = *(const uint2*)(h + (size_t)s0 * 256 + lane * 4);
      uint2 u1 = *(const uint2*)(h + (size_t)s1 * 256 + lane * 4);
      uint2 u2 = *(const uint2*)(h + (size_t)s2 * 256 + lane * 4);
      uint2 u3 = *(const uint2*)(h + (size_t)s3 * 256 + lane * 4);
      a0 += bf2f(u0.x & 0xffff) + bf2f(u1.x & 0xffff) + bf2f(u2.x & 0xffff) + bf2f(u3.x & 0xffff);
      a1 += bf2f(u0.x >> 16)    + bf2f(u1.x >> 16)    + bf2f(u2.x >> 16)    + bf2f(u3.x >> 16);
      a2 += bf2f(u0.y & 0xffff) + bf2f(u1.y & 0xffff) + bf2f(u2.y & 0xffff) + bf2f(u3.y & 0xffff);
      a3 += bf2f(u0.y >> 16)    + bf2f(u1.y >> 16)    + bf2f(u2.y >> 16)    + bf2f(u3.y >> 16);
    }
    for (; j < nread; ++j) {
      int s0 = sp[j];
      uint2 u0 = *(const uint2*)(h + (size_t)s0 * 256 + lane * 4);
      a0 += bf2f(u0.x & 0xffff);
      a1 += bf2f(u0.x >> 16);
      a2 += bf2f(u0.y & 0xffff);
      a3 += bf2f(u0.y >> 16);
    }
    float inv = 1.0f / (float)(d > 1 ? d : 1);
    uint2 o;
    o.x = (unsigned)f2bf(a0 * inv) | ((unsigned)f2bf(a1 * inv) << 16);
    o.y = (unsigned)f2bf(a2 * inv) | ((unsigned)f2bf(a3 * inv) << 16);
    *(uint2*)(mean + (size_t)node * 256 + lane * 4) = o;
  }
}

// ---------------------------------------------------------------------------
// P0 partition: x-cast 10000*512/4 = 1,280,000 | W transpose 393,216 |
// edge scatter 320,000.  (cursor pre-zeroed by hipMemsetAsync.)
#define P0_X 1280000
#define P0_W 393216
#define P0_TOT (P0_X + P0_W + N_EDGES)

__global__ __launch_bounds__(256, 2) void mega(
    const float* __restrict__ x, const unsigned* __restrict__ ei,
    const float* __restrict__ W0, const float* __restrict__ b0,
    const float* __restrict__ Wl1, const float* __restrict__ bl1,
    const float* __restrict__ Wr1,
    const float* __restrict__ Wl2, const float* __restrict__ bl2,
    const float* __restrict__ Wr2,
    ushort_t* __restrict__ xb, ushort_t* __restrict__ hb,
    ushort_t* __restrict__ o1b, ushort_t* __restrict__ mb,
    ushort_t* __restrict__ W0T, ushort_t* __restrict__ WT1,
    ushort_t* __restrict__ WT2,
    int* __restrict__ cursor, int* __restrict__ srcs, int* __restrict__ bar,
    float* __restrict__ out1, float* __restrict__ out2) {
  __shared__ ushort_t smem[64 * 520];   // 66,560 B; 2 blocks/CU

  const int b   = blockIdx.x;
  const int tid = threadIdx.x;

  // ---- P0: x cast->bf16 | weight transpose->bf16 | edge scatter ----------
  {
    int is64 = detect64(ei);
    for (int idx = b * NTH + tid; idx < P0_TOT; idx += NB * NTH) {
      if (idx < P0_X) {
        float4 f = *(const float4*)(x + (size_t)idx * 4);
        uint2 o;
        o.x = (unsigned)f2bf(f.x) | ((unsigned)f2bf(f.y) << 16);
        o.y = (unsigned)f2bf(f.z) | ((unsigned)f2bf(f.w) << 16);
        *(uint2*)(xb + (size_t)idx * 4) = o;
      } else if (idx < P0_X + P0_W) {
        int g = idx - P0_X;
        int mat = g >> 17;
        int r = g & 131071;
        int n = r >> 9, k = r & 511;
        float v;
        ushort_t* dst;
        if (mat == 0)      { v = W0[k * 256 + n]; dst = W0T; }
        else if (mat == 1) { v = (k < 256) ? Wl1[k * 256 + n] : Wr1[(k - 256) * 256 + n]; dst = WT1; }
        else               { v = (k < 256) ? Wl2[k * 256 + n] : Wr2[(k - 256) * 256 + n]; dst = WT2; }
        dst[r] = f2bf(v);
      } else {
        int e = idx - (P0_X + P0_W);
        int dd = load_idx(ei, N_EDGES + e, is64);
        int ss = load_idx(ei, e, is64);
        int pos = atomicAdd(&cursor[dd], 1);
        if (pos < CAP) srcs[(size_t)dd * CAP + pos] = ss;
      }
    }
  }
  gridbar(bar, 0);

  // ---- P1: h = xb @ W0T + b0 -> hb ---------------------------------------
  if (b < N_TILES)
    gemm_tile<0, 0, 0, 1, 0>(b, xb, nullptr, W0T, b0, nullptr, nullptr, hb,
                             smem, N_NODES);
  gridbar(bar, 1);

  // ---- P2: mean1 = bucket-mean(h) -> mb ----------------------------------
  agg_phase(hb, cursor, srcs, mb);
  gridbar(bar, 2);

  // ---- P3: out1 = relu([mb|hb]@WT1 + bl1) + hb ---------------------------
  if (b < N_TILES)
    gemm_tile<1, 1, 1, 1, 1>(b, mb, hb, WT1, bl1, hb, out1, o1b, smem, N_NODES);
  gridbar(bar, 3);

  // ---- P4: mean2 = bucket-mean(out1) -> mb -------------------------------
  agg_phase(o1b, cursor, srcs, mb);
  gridbar(bar, 4);

  // ---- P5: out2 = [mb|o1b]@WT2 + bl2 + o1b -------------------------------
  if (b < N_TILES)
    gemm_tile<0, 1, 1, 0, 1>(b, mb, o1b, WT2, bl2, o1b, out2, nullptr, smem,
                             N_NODES);
}

// ---------------------------------------------------------------------------
extern "C" void kernel_launch(void* const* d_in, const int* in_sizes, int n_in,
                              void* d_out, int out_size, void* d_ws, size_t ws_size,
                              hipStream_t stream) {
  const float*    x   = (const float*)d_in[0];
  const unsigned* ei  = (const unsigned*)d_in[1];
  const float*    W0  = (const float*)d_in[2];
  const float*    b0  = (const float*)d_in[3];
  const float*    Wl1 = (const float*)d_in[4];
  const float*    bl1 = (const float*)d_in[5];
  const float*    Wr1 = (const float*)d_in[6];
  const float*    Wl2 = (const float*)d_in[7];
  const float*    bl2 = (const float*)d_in[8];
  const float*    Wr2 = (const float*)d_in[9];

  char* ws = (char*)d_ws;
  size_t off = 0;
  auto alloc = [&](size_t bytes) {
    char* p = ws + off;
    off += (bytes + 255) & ~(size_t)255;
    return p;
  };
  ushort_t* xb  = (ushort_t*)alloc((size_t)N_NODES * 512 * 2);
  ushort_t* hb  = (ushort_t*)alloc((size_t)N_NODES * 256 * 2);
  ushort_t* o1b = (ushort_t*)alloc((size_t)N_NODES * 256 * 2);
  ushort_t* mb  = (ushort_t*)alloc((size_t)N_NODES * 256 * 2);
  ushort_t* W0T = (ushort_t*)alloc(256 * 512 * 2);
  ushort_t* WT1 = (ushort_t*)alloc(256 * 512 * 2);
  ushort_t* WT2 = (ushort_t*)alloc(256 * 512 * 2);
  int* zeroed = (int*)alloc((N_NODES + 16) * 4);   // cursor (10000) + bar (16)
  int* cursor = zeroed;
  int* bar    = zeroed + N_NODES;
  int* srcs   = (int*)alloc((size_t)N_NODES * CAP * 4);

  float* out1 = (float*)d_out;
  float* out2 = out1 + (size_t)N_NODES * DOUT;

  hipMemsetAsync(zeroed, 0, (N_NODES + 16) * 4, stream);
  mega<<<NB, NTH, 0, stream>>>(x, ei, W0, b0, Wl1, bl1, Wr1, Wl2, bl2, Wr2,
                               xb, hb, o1b, mb, W0T, WT1, WT2,
                               cursor, srcs, bar, out1, out2);
}